// Round 7
// baseline (478.740 us; speedup 1.0000x reference)
//
#include <hip/hip_runtime.h>
#include <math.h>

// Problem shapes (fixed by reference setup_inputs):
constexpr int Bc = 8, Hc = 384, Wc = 1280, Cc = 8;

// ---------------- gather kernel ----------------
// One thread per 2x2 OUTPUT QUAD. Source (h,w) contributes to pixel (py,px)
// iff |w+fx-px| < 1 and |h+fy-py| < 1. With |f|<=WIN=3 the contributing
// sources for a 2x2 quad lie in an 8x8 window (exactly one u64 mask).
// FMAX = WIN = 3 drops no taps (|d+f| >= 1 for |d| >= WIN+1, |f| <= WIN).
// Sources with |f|>3 (~21K of 3.9M) are appended to a compact list during
// staging and processed by a list-driven scatter kernel, stream-ordered
// after this kernel's plain overwrite stores.
//
// History: r3 11x11 one-pass = 232us; r6 7x7 two-pass = 237us; VALUBusy 27%
// -> latency-bound, not scan-bound. This version: quad threads share the
// scan (1 ds_read serves 4 px), share hit loads (1 ua/ub -> 32 FMAs), and
// software-pipeline the hit loop. Round-5 lesson: do NOT stage U in LDS.
constexpr int TH = 32, TW = 32;              // output tile (256 thr x 2x2 quad)
constexpr int WIN = 3;                        // window half-width
constexpr float FMAX = 3.0f;                  // = WIN (exactness bound)
constexpr int RH = TH + 2 * WIN;              // 38
constexpr int RW = TW + 2 * WIN;              // 38
constexpr int PSTR = RW + 1;                  // 39: padded LDS row stride
constexpr int TILES_X = Wc / TW;              // 40
constexpr int TILES_Y = Hc / TH;              // 12
constexpr int BLK = 256;
constexpr unsigned LIST_CAP = 262144;         // 1 MB of u32 entries
constexpr size_t WS_NEED = 16 + (size_t)LIST_CAP * 4;

__device__ __forceinline__ void fma4(float4& a, float4 u, float w)
{
    a.x = fmaf(u.x, w, a.x); a.y = fmaf(u.y, w, a.y);
    a.z = fmaf(u.z, w, a.z); a.w = fmaf(u.w, w, a.w);
}

__global__ __launch_bounds__(BLK) void fwd_warp_gather(
    const float* __restrict__ U, const float* __restrict__ flo,
    float* __restrict__ out, unsigned* __restrict__ ws, int do_append)
{
    // splat coords (x,y)=(w+fx,h+fy) per source; sentinel -1e9 never hits.
    __shared__ float2 sxy[RH * PSTR];         // 38*39*8 = 11856 B

    int tile = blockIdx.x;
    int b  = tile / (TILES_X * TILES_Y);
    int r  = tile % (TILES_X * TILES_Y);
    int Y0 = (r / TILES_X) * TH;
    int X0 = (r % TILES_X) * TW;
    int t  = threadIdx.x;

    const float2* flo2 = reinterpret_cast<const float2*>(flo);
    const float4* u4   = reinterpret_cast<const float4*>(U);

    // ---- stage splat coords (coalesced float2 reads), append outliers ----
    for (int i = t; i < RH * RW; i += BLK) {
        int sy = i / RW, sx = i - sy * RW;
        int h = Y0 - WIN + sy;
        int w = X0 - WIN + sx;
        bool inimg = ((unsigned)h < (unsigned)Hc) & ((unsigned)w < (unsigned)Wc);
        int hc = min(max(h, 0), Hc - 1);
        int wc = min(max(w, 0), Wc - 1);
        int sidx = (b * Hc + hc) * Wc + wc;
        float2 f = flo2[sidx];
        bool inl = (fabsf(f.x) <= FMAX) && (fabsf(f.y) <= FMAX);
        float2 v = (inimg && inl) ? make_float2((float)w + f.x, (float)h + f.y)
                                  : make_float2(-1e9f, -1e9f);
        sxy[sy * PSTR + sx] = v;
        // exact complement predicate, interior ownership -> appended once
        if (do_append && inimg && !inl &&
            sy >= WIN && sy < WIN + TH && sx >= WIN && sx < WIN + TW) {
            unsigned pos = atomicAdd(ws, 1u);
            if (pos < LIST_CAP) ws[4 + pos] = (unsigned)sidx;
        }
    }
    __syncthreads();

    int qy = t >> 4, qx = t & 15;
    int lpy = qy * 2, lpx = qx * 2;           // quad's pixel offset in tile
    int py = Y0 + lpy, px = X0 + lpx;         // quad's top-left pixel
    float cx = (float)px + 0.5f;              // quad center
    float cy = (float)py + 0.5f;

    // ---- pass 1: one u64 union mask over the 8x8 window (bit = dy*8+dx) ----
    // hit-any-quad-pixel  <=>  max(|x-cx|,|y-cy|) < 1.5  (boundary cases have
    // exactly-zero weight; excluding them is identity). Sentinels never pass.
    unsigned long long mask = 0ull;
    #pragma unroll
    for (int dy = 0; dy < 8; ++dy) {
        int rb = (lpy + dy) * PSTR + lpx;
        #pragma unroll
        for (int dx = 0; dx < 8; ++dx) {
            float2 s = sxy[rb + dx];
            float m = fmaxf(fabsf(s.x - cx), fabsf(s.y - cy));
            unsigned long long hit = (m < 1.5f) ? 1ull : 0ull;
            mask |= hit << (dy * 8 + dx);
        }
    }

    // ---- pass 2: software-pipelined hit loop, 1 load pair -> 32 FMAs ----
    // per-pixel weight max(0,1-|x-px|)*max(0,1-|y-py|) == reference bilinear
    // weight (incl. zero at boundary and clamp-zeroed taps; sentinel -> 0).
    float4 aA0 = {0,0,0,0}, aB0 = {0,0,0,0};  // pixel (py  , px  )
    float4 aA1 = {0,0,0,0}, aB1 = {0,0,0,0};  // pixel (py  , px+1)
    float4 aA2 = {0,0,0,0}, aB2 = {0,0,0,0};  // pixel (py+1, px  )
    float4 aA3 = {0,0,0,0}, aB3 = {0,0,0,0};  // pixel (py+1, px+1)

    int sbase = (b * Hc + Y0 - WIN) * Wc + (X0 - WIN);
    float pxf = (float)px, pyf = (float)py;

    float2 s; float4 ua, ub;
    bool have = (mask != 0ull);
    if (have) {
        int bit = __builtin_ctzll(mask); mask &= mask - 1;
        int dy = bit >> 3, dx = bit & 7;
        s = sxy[(lpy + dy) * PSTR + lpx + dx];
        int sidx = sbase + (lpy + dy) * Wc + (lpx + dx);
        ua = u4[(size_t)sidx * 2];
        ub = u4[(size_t)sidx * 2 + 1];
    }
    while (have) {
        // issue next hit's LDS + global loads before current FMAs
        float2 sn; float4 uan, ubn;
        bool haven = (mask != 0ull);
        if (haven) {
            int bit = __builtin_ctzll(mask); mask &= mask - 1;
            int dy = bit >> 3, dx = bit & 7;
            sn = sxy[(lpy + dy) * PSTR + lpx + dx];
            int sidx = sbase + (lpy + dy) * Wc + (lpx + dx);
            uan = u4[(size_t)sidx * 2];
            ubn = u4[(size_t)sidx * 2 + 1];
        }
        float tx = s.x - pxf, ty = s.y - pyf;
        float bx0 = fmaxf(0.f, 1.f - fabsf(tx));
        float bx1 = fmaxf(0.f, 1.f - fabsf(tx - 1.f));
        float by0 = fmaxf(0.f, 1.f - fabsf(ty));
        float by1 = fmaxf(0.f, 1.f - fabsf(ty - 1.f));
        float w00 = bx0 * by0, w01 = bx1 * by0;
        float w10 = bx0 * by1, w11 = bx1 * by1;
        fma4(aA0, ua, w00); fma4(aB0, ub, w00);
        fma4(aA1, ua, w01); fma4(aB1, ub, w01);
        fma4(aA2, ua, w10); fma4(aB2, ub, w10);
        fma4(aA3, ua, w11); fma4(aB3, ub, w11);
        s = sn; ua = uan; ub = ubn; have = haven;
    }

    // ---- epilogue: overwrite my 4 pixels (plain stores, no atomics) ----
    float4* o4 = reinterpret_cast<float4*>(out);
    size_t obase = (size_t)(b * Hc + py) * Wc + px;
    o4[obase * 2]            = aA0; o4[obase * 2 + 1]            = aB0;
    o4[(obase + 1) * 2]      = aA1; o4[(obase + 1) * 2 + 1]      = aB1;
    o4[(obase + Wc) * 2]     = aA2; o4[(obase + Wc) * 2 + 1]     = aB2;
    o4[(obase + Wc + 1) * 2] = aA3; o4[(obase + Wc + 1) * 2 + 1] = aB3;
}

// ---------------- list-driven outlier scatter ----------------
// Processes ONLY the compacted outlier list (no full flo scan). Reference
// semantics (clamp + zero-weight skip), global atomics, stream-ordered
// after the gather's plain stores.
__global__ __launch_bounds__(BLK) void fwd_warp_outlier_list(
    const float* __restrict__ U, const float* __restrict__ flo,
    float* __restrict__ out, const unsigned* __restrict__ ws)
{
    unsigned n = min(ws[0], LIST_CAP);
    for (unsigned i = blockIdx.x * BLK + threadIdx.x; i < n;
         i += gridDim.x * BLK) {
        int sidx = (int)ws[4 + i];
        int w = sidx % Wc;
        int h = (sidx / Wc) % Hc;
        float2 f = reinterpret_cast<const float2*>(flo)[sidx];

        float x = (float)w + f.x;
        float y = (float)h + f.y;
        float x0f = floorf(x), y0f = floorf(y);
        int x0 = (int)x0f, y0 = (int)y0f;
        float wx[2] = { (x0f + 1.0f) - x, x - x0f };
        float wy[2] = { (y0f + 1.0f) - y, y - y0f };

        const float4* u4 = reinterpret_cast<const float4*>(U);
        float4 ua = u4[(size_t)sidx * 2];
        float4 ub = u4[(size_t)sidx * 2 + 1];
        int bbase = sidx - (h * Wc + w);      // b*Hc*Wc

        #pragma unroll
        for (int j = 0; j < 2; ++j) {
            #pragma unroll
            for (int k = 0; k < 2; ++k) {
                int ty = y0 + j, tx = x0 + k;
                if ((unsigned)ty < (unsigned)Hc && (unsigned)tx < (unsigned)Wc) {
                    float wgt = wx[k] * wy[j];
                    if (wgt != 0.0f) {
                        float* p = out + ((size_t)(bbase + ty * Wc + tx)) * 8;
                        atomicAdd(p + 0, ua.x * wgt);
                        atomicAdd(p + 1, ua.y * wgt);
                        atomicAdd(p + 2, ua.z * wgt);
                        atomicAdd(p + 3, ua.w * wgt);
                        atomicAdd(p + 4, ub.x * wgt);
                        atomicAdd(p + 5, ub.y * wgt);
                        atomicAdd(p + 6, ub.z * wgt);
                        atomicAdd(p + 7, ub.w * wgt);
                    }
                }
            }
        }
    }
}

// ---------------- fallback full-scan outlier (only if ws too small) ----------------
__global__ __launch_bounds__(BLK) void fwd_warp_outlier_scan(
    const float* __restrict__ U, const float* __restrict__ flo,
    float* __restrict__ out)
{
    int tid = blockIdx.x * BLK + threadIdx.x;
    int total = Bc * Hc * Wc;
    if (tid >= total) return;
    float2 f = reinterpret_cast<const float2*>(flo)[tid];
    if (fabsf(f.x) <= FMAX && fabsf(f.y) <= FMAX) return;

    int w = tid % Wc;
    int h = (tid / Wc) % Hc;
    float x = (float)w + f.x;
    float y = (float)h + f.y;
    float x0f = floorf(x), y0f = floorf(y);
    int x0 = (int)x0f, y0 = (int)y0f;
    float wx[2] = { (x0f + 1.0f) - x, x - x0f };
    float wy[2] = { (y0f + 1.0f) - y, y - y0f };

    const float4* u4 = reinterpret_cast<const float4*>(U);
    float4 ua = u4[(size_t)tid * 2];
    float4 ub = u4[(size_t)tid * 2 + 1];
    int bbase = tid - (h * Wc + w);

    #pragma unroll
    for (int j = 0; j < 2; ++j) {
        #pragma unroll
        for (int k = 0; k < 2; ++k) {
            int ty = y0 + j, tx = x0 + k;
            if ((unsigned)ty < (unsigned)Hc && (unsigned)tx < (unsigned)Wc) {
                float wgt = wx[k] * wy[j];
                if (wgt != 0.0f) {
                    float* p = out + ((size_t)(bbase + ty * Wc + tx)) * 8;
                    atomicAdd(p + 0, ua.x * wgt);
                    atomicAdd(p + 1, ua.y * wgt);
                    atomicAdd(p + 2, ua.z * wgt);
                    atomicAdd(p + 3, ua.w * wgt);
                    atomicAdd(p + 4, ub.x * wgt);
                    atomicAdd(p + 5, ub.y * wgt);
                    atomicAdd(p + 6, ub.z * wgt);
                    atomicAdd(p + 7, ub.w * wgt);
                }
            }
        }
    }
}

extern "C" void kernel_launch(void* const* d_in, const int* in_sizes, int n_in,
                              void* d_out, int out_size, void* d_ws, size_t ws_size,
                              hipStream_t stream)
{
    const float* U   = (const float*)d_in[0];
    const float* flo = (const float*)d_in[1];
    float* out = (float*)d_out;
    unsigned* ws = (unsigned*)d_ws;

    bool use_list = (ws != nullptr) && (ws_size >= WS_NEED);
    int grid_g = Bc * TILES_X * TILES_Y;            // 3840 tiles

    if (use_list) {
        hipMemsetAsync(d_ws, 0, 16, stream);        // zero the append counter
        fwd_warp_gather<<<grid_g, BLK, 0, stream>>>(U, flo, out, ws, 1);
        fwd_warp_outlier_list<<<256, BLK, 0, stream>>>(U, flo, out, ws);
    } else {
        fwd_warp_gather<<<grid_g, BLK, 0, stream>>>(U, flo, out, ws, 0);
        int grid_o = (Bc * Hc * Wc + BLK - 1) / BLK;
        fwd_warp_outlier_scan<<<grid_o, BLK, 0, stream>>>(U, flo, out);
    }
}

// Round 8
// 444.307 us; speedup vs baseline: 1.0775x; 1.0775x over previous
//
#include <hip/hip_runtime.h>
#include <math.h>

// Problem shapes (fixed by reference setup_inputs):
constexpr int Bc = 8, Hc = 384, Wc = 1280, Cc = 8;

// ---------------- gather kernel ----------------
// One thread per OUTPUT pixel (r6 structure, known best). Source (h,w)
// contributes to pixel (py,px) iff |w+fx-px| < 1 and |h+fy-py| < 1. With
// |f|<=WIN=3 contributing sources lie in the 7x7 window EXACTLY (a source
// at integer offset d >= WIN+1 with |f| <= WIN has |d+f| >= 1 -> fails the
// strict <1 test). Sources with |f|>3 (~21K of 3.9M) are appended to a
// compact list during staging and processed by a list-driven scatter
// kernel, stream-ordered after this kernel's plain overwrite stores.
//
// r8 change: __launch_bounds__(256,4) lifts the VGPR cap to 128 (every
// prior round the compiler allocated 16-36 VGPRs and serialized all
// memory phases into load->wait->use chains), plus a depth-2 pipelined
// hit loop. Rounds 3/5/6 eliminated scan-VALU, pass-2 feed source, and
// staging volume as bottlenecks; register starvation is the one cause
// consistent with all profiles.
constexpr int TH = 16, TW = 16;              // output tile per block (256 thr)
constexpr int WIN = 3;                        // window half-width
constexpr float FMAX = 3.0f;                  // = WIN (exactness bound)
constexpr int RH = TH + 2 * WIN;              // 22
constexpr int RW = TW + 2 * WIN;              // 22
constexpr int PSTR = RW + 1;                  // 23: padded LDS row stride
constexpr int TILES_X = Wc / TW;              // 80
constexpr int TILES_Y = Hc / TH;              // 24
constexpr int BLK = 256;
constexpr unsigned LIST_CAP = 262144;         // 1 MB of u32 entries
constexpr size_t WS_NEED = 16 + (size_t)LIST_CAP * 4;

__global__ __launch_bounds__(BLK, 4) void fwd_warp_gather(
    const float* __restrict__ U, const float* __restrict__ flo,
    float* __restrict__ out, unsigned* __restrict__ ws, int do_append)
{
    // splat coords (x,y)=(w+fx,h+fy) per source; sentinel -1e9 never hits.
    __shared__ float2 sxy[RH * PSTR];         // 4048 B

    int tile = blockIdx.x;
    int b  = tile / (TILES_X * TILES_Y);
    int r  = tile % (TILES_X * TILES_Y);
    int Y0 = (r / TILES_X) * TH;
    int X0 = (r % TILES_X) * TW;
    int t  = threadIdx.x;

    const float2* flo2 = reinterpret_cast<const float2*>(flo);
    const float4* u4   = reinterpret_cast<const float4*>(U);

    // ---- stage splat coords (coalesced float2 reads), append outliers ----
    for (int i = t; i < RH * RW; i += BLK) {
        int sy = i / RW, sx = i - sy * RW;
        int h = Y0 - WIN + sy;
        int w = X0 - WIN + sx;
        bool inimg = ((unsigned)h < (unsigned)Hc) & ((unsigned)w < (unsigned)Wc);
        int hc = min(max(h, 0), Hc - 1);
        int wc = min(max(w, 0), Wc - 1);
        int sidx = (b * Hc + hc) * Wc + wc;
        float2 f = flo2[sidx];
        bool inl = (fabsf(f.x) <= FMAX) && (fabsf(f.y) <= FMAX);
        float2 v = (inimg && inl) ? make_float2((float)w + f.x, (float)h + f.y)
                                  : make_float2(-1e9f, -1e9f);
        sxy[sy * PSTR + sx] = v;
        // exact complement predicate, interior ownership -> appended once
        if (do_append && inimg && !inl &&
            sy >= WIN && sy < WIN + TH && sx >= WIN && sx < WIN + TW) {
            unsigned pos = atomicAdd(ws, 1u);
            if (pos < LIST_CAP) ws[4 + pos] = (unsigned)sidx;
        }
    }
    __syncthreads();

    int lpy = t >> 4, lpx = t & 15;
    int py = Y0 + lpy, px = X0 + lpx;
    float pxf = (float)px, pyf = (float)py;
    int pixbase = (b * Hc + py) * Wc + px;

    // ---- pass 1: branchless 49-bit hit mask (packed dy*8+dx) ----
    unsigned long long mask = 0ull;
    #pragma unroll
    for (int dy = 0; dy < 2 * WIN + 1; ++dy) {
        int rb = (lpy + dy) * PSTR + lpx;
        #pragma unroll
        for (int dx = 0; dx < 2 * WIN + 1; ++dx) {
            float2 s = sxy[rb + dx];
            // strict < 1: boundary taps have exactly-zero weight; adding
            // zero is identity. Sentinels never pass.
            float m = fmaxf(fabsf(s.x - pxf), fabsf(s.y - pyf));
            unsigned long long hit = (m < 1.0f) ? 1ull : 0ull;
            mask |= hit << (dy * 8 + dx);
        }
    }

    // ---- pass 2: depth-2 pipelined hit loop, full lane density ----
    // next hit's LDS+global loads issue under current hit's weight+FMAs.
    float a0 = 0.f, a1 = 0.f, a2 = 0.f, a3 = 0.f;
    float a4 = 0.f, a5 = 0.f, a6 = 0.f, a7 = 0.f;

    float2 s; float4 ua, ub;
    bool have = (mask != 0ull);
    if (have) {
        int bit = __builtin_ctzll(mask); mask &= mask - 1;
        int dy = bit >> 3, dx = bit & 7;
        s = sxy[(lpy + dy) * PSTR + lpx + dx];
        int sidx = pixbase + (dy - WIN) * Wc + (dx - WIN);
        ua = u4[(size_t)sidx * 2];
        ub = u4[(size_t)sidx * 2 + 1];
    }
    while (have) {
        float2 sn; float4 uan, ubn;
        bool haven = (mask != 0ull);
        if (haven) {
            int bit = __builtin_ctzll(mask); mask &= mask - 1;
            int dy = bit >> 3, dx = bit & 7;
            sn = sxy[(lpy + dy) * PSTR + lpx + dx];
            int sidx = pixbase + (dy - WIN) * Wc + (dx - WIN);
            uan = u4[(size_t)sidx * 2];
            ubn = u4[(size_t)sidx * 2 + 1];
        }
        // (1-|x-px|)(1-|y-py|) == reference bilinear weight for this tap
        float wgt = (1.0f - fabsf(s.x - pxf)) * (1.0f - fabsf(s.y - pyf));
        a0 = fmaf(ua.x, wgt, a0); a1 = fmaf(ua.y, wgt, a1);
        a2 = fmaf(ua.z, wgt, a2); a3 = fmaf(ua.w, wgt, a3);
        a4 = fmaf(ub.x, wgt, a4); a5 = fmaf(ub.y, wgt, a5);
        a6 = fmaf(ub.z, wgt, a6); a7 = fmaf(ub.w, wgt, a7);
        s = sn; ua = uan; ub = ubn; have = haven;
    }

    // plain coalesced stores (no atomics): full overwrite of my pixel
    float4 o0 = {a0, a1, a2, a3};
    float4 o1 = {a4, a5, a6, a7};
    reinterpret_cast<float4*>(out)[(size_t)pixbase * 2]     = o0;
    reinterpret_cast<float4*>(out)[(size_t)pixbase * 2 + 1] = o1;
}

// ---------------- list-driven outlier scatter ----------------
// Processes ONLY the compacted outlier list (no full flo scan). Reference
// semantics (clamp + zero-weight skip), global atomics, stream-ordered
// after the gather's plain stores.
__global__ __launch_bounds__(BLK) void fwd_warp_outlier_list(
    const float* __restrict__ U, const float* __restrict__ flo,
    float* __restrict__ out, const unsigned* __restrict__ ws)
{
    unsigned n = min(ws[0], LIST_CAP);
    for (unsigned i = blockIdx.x * BLK + threadIdx.x; i < n;
         i += gridDim.x * BLK) {
        int sidx = (int)ws[4 + i];
        int w = sidx % Wc;
        int h = (sidx / Wc) % Hc;
        float2 f = reinterpret_cast<const float2*>(flo)[sidx];

        float x = (float)w + f.x;
        float y = (float)h + f.y;
        float x0f = floorf(x), y0f = floorf(y);
        int x0 = (int)x0f, y0 = (int)y0f;
        float wx[2] = { (x0f + 1.0f) - x, x - x0f };
        float wy[2] = { (y0f + 1.0f) - y, y - y0f };

        const float4* u4 = reinterpret_cast<const float4*>(U);
        float4 ua = u4[(size_t)sidx * 2];
        float4 ub = u4[(size_t)sidx * 2 + 1];
        int bbase = sidx - (h * Wc + w);      // b*Hc*Wc

        #pragma unroll
        for (int j = 0; j < 2; ++j) {
            #pragma unroll
            for (int k = 0; k < 2; ++k) {
                int ty = y0 + j, tx = x0 + k;
                if ((unsigned)ty < (unsigned)Hc && (unsigned)tx < (unsigned)Wc) {
                    float wgt = wx[k] * wy[j];
                    if (wgt != 0.0f) {
                        float* p = out + ((size_t)(bbase + ty * Wc + tx)) * 8;
                        atomicAdd(p + 0, ua.x * wgt);
                        atomicAdd(p + 1, ua.y * wgt);
                        atomicAdd(p + 2, ua.z * wgt);
                        atomicAdd(p + 3, ua.w * wgt);
                        atomicAdd(p + 4, ub.x * wgt);
                        atomicAdd(p + 5, ub.y * wgt);
                        atomicAdd(p + 6, ub.z * wgt);
                        atomicAdd(p + 7, ub.w * wgt);
                    }
                }
            }
        }
    }
}

// ---------------- fallback full-scan outlier (only if ws too small) ----------------
__global__ __launch_bounds__(BLK) void fwd_warp_outlier_scan(
    const float* __restrict__ U, const float* __restrict__ flo,
    float* __restrict__ out)
{
    int tid = blockIdx.x * BLK + threadIdx.x;
    int total = Bc * Hc * Wc;
    if (tid >= total) return;
    float2 f = reinterpret_cast<const float2*>(flo)[tid];
    if (fabsf(f.x) <= FMAX && fabsf(f.y) <= FMAX) return;

    int w = tid % Wc;
    int h = (tid / Wc) % Hc;
    float x = (float)w + f.x;
    float y = (float)h + f.y;
    float x0f = floorf(x), y0f = floorf(y);
    int x0 = (int)x0f, y0 = (int)y0f;
    float wx[2] = { (x0f + 1.0f) - x, x - x0f };
    float wy[2] = { (y0f + 1.0f) - y, y - y0f };

    const float4* u4 = reinterpret_cast<const float4*>(U);
    float4 ua = u4[(size_t)tid * 2];
    float4 ub = u4[(size_t)tid * 2 + 1];
    int bbase = tid - (h * Wc + w);

    #pragma unroll
    for (int j = 0; j < 2; ++j) {
        #pragma unroll
        for (int k = 0; k < 2; ++k) {
            int ty = y0 + j, tx = x0 + k;
            if ((unsigned)ty < (unsigned)Hc && (unsigned)tx < (unsigned)Wc) {
                float wgt = wx[k] * wy[j];
                if (wgt != 0.0f) {
                    float* p = out + ((size_t)(bbase + ty * Wc + tx)) * 8;
                    atomicAdd(p + 0, ua.x * wgt);
                    atomicAdd(p + 1, ua.y * wgt);
                    atomicAdd(p + 2, ua.z * wgt);
                    atomicAdd(p + 3, ua.w * wgt);
                    atomicAdd(p + 4, ub.x * wgt);
                    atomicAdd(p + 5, ub.y * wgt);
                    atomicAdd(p + 6, ub.z * wgt);
                    atomicAdd(p + 7, ub.w * wgt);
                }
            }
        }
    }
}

extern "C" void kernel_launch(void* const* d_in, const int* in_sizes, int n_in,
                              void* d_out, int out_size, void* d_ws, size_t ws_size,
                              hipStream_t stream)
{
    const float* U   = (const float*)d_in[0];
    const float* flo = (const float*)d_in[1];
    float* out = (float*)d_out;
    unsigned* ws = (unsigned*)d_ws;

    bool use_list = (ws != nullptr) && (ws_size >= WS_NEED);
    int grid_g = Bc * TILES_X * TILES_Y;            // 15360 tiles

    if (use_list) {
        hipMemsetAsync(d_ws, 0, 16, stream);        // zero the append counter
        fwd_warp_gather<<<grid_g, BLK, 0, stream>>>(U, flo, out, ws, 1);
        fwd_warp_outlier_list<<<256, BLK, 0, stream>>>(U, flo, out, ws);
    } else {
        fwd_warp_gather<<<grid_g, BLK, 0, stream>>>(U, flo, out, ws, 0);
        int grid_o = (Bc * Hc * Wc + BLK - 1) / BLK;
        fwd_warp_outlier_scan<<<grid_o, BLK, 0, stream>>>(U, flo, out);
    }
}